// Round 4
// baseline (143.532 us; speedup 1.0000x reference)
//
#include <hip/hip_runtime.h>
#include <hip/hip_bf16.h>

#define B_  8
#define S_  4096
#define DM  1024
#define DO  1024

typedef __attribute__((ext_vector_type(4))) float f32x4;
typedef __attribute__((ext_vector_type(8))) short bf16x8;

__device__ inline unsigned int pkbf(float a, float b) {
    __hip_bfloat162 h = __float22bfloat162_rn(float2{a, b});
    union { __hip_bfloat162 h2; unsigned int u; } cv;
    cv.h2 = h;
    return cv.u;
}

// ---- prep: wpack[b][nb][kt] 32KB tiles: [half][colh:128][k-swizzled 128B] bf16 ----
__global__ __launch_bounds__(256) void prep_wpack(
    const float* __restrict__ W, const int* __restrict__ sel_idx,
    const float* __restrict__ sel_probs, unsigned short* __restrict__ wpack)
{
    const int kt = blockIdx.x, nb = blockIdx.y, b = blockIdx.z;
    const int i0 = sel_idx[b*2+0], i1 = sel_idx[b*2+1];
    const float p0 = sel_probs[b*2+0], p1 = sel_probs[b*2+1];
    const int col = threadIdx.x;              // 0..255
    const int half = col >> 7, colh = col & 127;

    const float* w0 = W + (size_t)i0 * DM * DO + (size_t)(kt * 64) * DO + nb * 256 + col;
    const float* w1 = W + (size_t)i1 * DM * DO + (size_t)(kt * 64) * DO + nb * 256 + col;

    char* dst = (char*)wpack + ((((size_t)b * 4 + nb) * 16 + kt) << 15)
              + half * 16384 + colh * 128;

    #pragma unroll
    for (int g = 0; g < 8; ++g) {
        float v[8];
        #pragma unroll
        for (int j = 0; j < 8; ++j)
            v[j] = p0 * w0[(size_t)(g * 8 + j) * DO] + p1 * w1[(size_t)(g * 8 + j) * DO];
        uint4 u;
        u.x = pkbf(v[0], v[1]); u.y = pkbf(v[2], v[3]);
        u.z = pkbf(v[4], v[5]); u.w = pkbf(v[6], v[7]);
        *reinterpret_cast<uint4*>(dst + ((g * 16) ^ ((colh & 7) << 4))) = u;
    }
}

__global__ __launch_bounds__(256) void prep_beff(
    const float* __restrict__ bias, const int* __restrict__ sel_idx,
    const float* __restrict__ sel_probs, float* __restrict__ beff)
{
    const int b = blockIdx.x;
    const int i0 = sel_idx[b*2+0], i1 = sel_idx[b*2+1];
    const float p0 = sel_probs[b*2+0], p1 = sel_probs[b*2+1];
    for (int o = threadIdx.x; o < DO; o += blockDim.x)
        beff[(size_t)b * DO + o] = p0 * bias[(size_t)i0 * DO + o]
                                 + p1 * bias[(size_t)i1 * DO + o];
}

// ---- GEMM: 256x256, BK=64, 8 waves (2Mx4N). A+B both double-buffered (128KB).
// ONE barrier per K-step; fragment reads software-pipelined one cluster ahead;
// compiler emits counted lgkm waits -> LDS pipe drains under MFMA clusters. ----
__global__ __launch_bounds__(512, 1) void gemm8(
    const float* __restrict__ X, const unsigned short* __restrict__ wpack,
    const float* __restrict__ beff, float* __restrict__ out)
{
    extern __shared__ char lds[];   // A: 0 / 32K ; B: 64K / 96K

    const int id = blockIdx.x;
    const int swz = (id & 7) * 64 + (id >> 3);   // XCD-chunked (512 = 8*64, bijective)
    const int b  = swz >> 6;
    const int bm = (swz & 63) >> 2;
    const int nb = swz & 3;

    const int t = threadIdx.x;
    const int wave = t >> 6, lane = t & 63;
    const int wm = wave >> 2, wn = wave & 3;     // 2x4 grid, 128x64 out per wave
    const int fr = lane & 15, fq = lane >> 4;

    const int s_row = t >> 3;                    // A staging: 0..63
    const int s_g   = t & 7;
    const float* xbase = X + ((size_t)(b * S_ + bm * 256 + s_row)) * DM + s_g * 8;
    const char* wtile0 = (const char*)(wpack + (((size_t)b * 4 + nb) * 16) * 16384);

    const int swz0 = (fq * 16) ^ ((fr & 7) << 4);
    const int swz1 = (64 + fq * 16) ^ ((fr & 7) << 4);
    const int aTb = wm * 16384 + fr * 128;                               // + mf*2048 + swzK
    const int bTb = (wn >> 1) * 16384 + ((wn & 1) * 64 + fr) * 128;      // + nf*2048 + swzK

    f32x4 acc[8][4] = {};
    float4 ax[8];

#define LOAD_X(KT)                                                            \
    _Pragma("unroll")                                                         \
    for (int p = 0; p < 4; ++p) {                                             \
        ax[p*2]   = *reinterpret_cast<const float4*>(xbase + (size_t)p*64*DM + (KT)*64);     \
        ax[p*2+1] = *reinterpret_cast<const float4*>(xbase + (size_t)p*64*DM + (KT)*64 + 4); \
    }

#define STAGE_B(KT, BOFF)                                                     \
    {                                                                         \
        const char* gB = wtile0 + (size_t)(KT) * 32768;                       \
        _Pragma("unroll")                                                     \
        for (int i = 0; i < 4; ++i)                                           \
            __builtin_amdgcn_global_load_lds(                                 \
                (const __attribute__((address_space(1))) void*)(gB + wave*4096 + i*1024 + lane*16), \
                (__attribute__((address_space(3))) void*)(lds + (BOFF) + wave*4096 + i*1024),       \
                16, 0, 0);                                                    \
    }

#define WRITE_A(AOFF)                                                         \
    _Pragma("unroll")                                                         \
    for (int p = 0; p < 4; ++p) {                                             \
        const int row = p * 64 + s_row;                                       \
        const int half = row >> 7, rowh = row & 127;                          \
        uint4 u;                                                              \
        u.x = pkbf(ax[p*2].x, ax[p*2].y);     u.y = pkbf(ax[p*2].z, ax[p*2].w);     \
        u.z = pkbf(ax[p*2+1].x, ax[p*2+1].y); u.w = pkbf(ax[p*2+1].z, ax[p*2+1].w); \
        *reinterpret_cast<uint4*>(lds + (AOFF) + half*16384 + rowh*128        \
                                  + ((s_g*16) ^ ((rowh & 7) << 4))) = u;      \
    }

#define READ_A4(DST, AOFF, MFBASE, SWZ)                                       \
    _Pragma("unroll")                                                         \
    for (int m = 0; m < 4; ++m)                                               \
        DST[m] = *reinterpret_cast<const bf16x8*>(lds + (AOFF) + aTb + ((MFBASE)+m)*2048 + (SWZ));

#define READ_B4(DST, BOFF, SWZ)                                               \
    _Pragma("unroll")                                                         \
    for (int nf = 0; nf < 4; ++nf)                                            \
        DST[nf] = *reinterpret_cast<const bf16x8*>(lds + (BOFF) + bTb + nf*2048 + (SWZ));

#define MFMA16(MFBASE, AF, BK)                                                \
    __builtin_amdgcn_s_setprio(1);                                            \
    _Pragma("unroll")                                                         \
    for (int m = 0; m < 4; ++m) {                                             \
        _Pragma("unroll")                                                     \
        for (int nf = 0; nf < 4; ++nf)                                        \
            acc[(MFBASE)+m][nf] = __builtin_amdgcn_mfma_f32_16x16x32_bf16(    \
                AF[m], BK[nf], acc[(MFBASE)+m][nf], 0, 0, 0);                 \
    }                                                                         \
    __builtin_amdgcn_s_setprio(0);

    // ---------- prologue: X(0) + B(0), write A(0), land everything ----------
    LOAD_X(0);
    __builtin_amdgcn_sched_barrier(0);
    STAGE_B(0, 65536);
    __builtin_amdgcn_sched_barrier(0);
    WRITE_A(0);                                   // compiler: counted vmcnt for ax
    asm volatile("s_waitcnt vmcnt(0) lgkmcnt(0)" ::: "memory");
    __builtin_amdgcn_s_barrier();
    __builtin_amdgcn_sched_barrier(0);

    bf16x8 afA[4], afB[4], afC[4], afD[4], bksA[4], bksB[4];
    int a_cur = 0, a_nxt = 32768, b_cur = 65536, b_nxt = 98304;

    READ_A4(afA, a_cur, 0, swz0);
    READ_B4(bksA, b_cur, swz0);

    #pragma unroll 1
    for (int kt = 0; kt < 15; ++kt) {
        // head: X(kt+1) -> regs (oldest vm ops), B(kt+1) -> b_nxt
        LOAD_X(kt + 1);
        __builtin_amdgcn_sched_barrier(0);
        STAGE_B(kt + 1, b_nxt);
        __builtin_amdgcn_sched_barrier(0);

        // pipelined clusters: reads for p+1 issued before MFMA p
        READ_A4(afB, a_cur, 4, swz0);
        MFMA16(0, afA, bksA);

        READ_A4(afC, a_cur, 0, swz1);
        READ_B4(bksB, b_cur, swz1);
        MFMA16(4, afB, bksA);

        READ_A4(afD, a_cur, 4, swz1);
        MFMA16(0, afC, bksB);

        // tail: convert+write A(kt+1); single barrier of the K-step
        WRITE_A(a_nxt);                           // compiler: vmcnt(4) for ax
        asm volatile("s_waitcnt vmcnt(0) lgkmcnt(0)" ::: "memory");
        __builtin_amdgcn_s_barrier();
        __builtin_amdgcn_sched_barrier(0);

        // post-barrier: issue next-kt p0 reads; cover with reg-resident cluster
        READ_A4(afA, a_nxt, 0, swz0);
        READ_B4(bksA, b_nxt, swz0);
        MFMA16(4, afD, bksB);

        int tmp = a_cur; a_cur = a_nxt; a_nxt = tmp;
        tmp = b_cur; b_cur = b_nxt; b_nxt = tmp;
    }

    // ---------- kt = 15 (no staging) ----------
    READ_A4(afB, a_cur, 4, swz0);
    MFMA16(0, afA, bksA);
    READ_A4(afC, a_cur, 0, swz1);
    READ_B4(bksB, b_cur, swz1);
    MFMA16(4, afB, bksA);
    READ_A4(afD, a_cur, 4, swz1);
    MFMA16(0, afC, bksB);
    MFMA16(4, afD, bksB);

    // ---------- epilogue: bias + sigmoid, fp32 store ----------
    const float* be = beff + (size_t)b * DO + nb * 256 + wn * 64;
    float bv[4];
    #pragma unroll
    for (int nf = 0; nf < 4; ++nf) bv[nf] = be[nf * 16 + fr];

    float* ob = out + ((size_t)(b * S_ + bm * 256 + wm * 128)) * DO + nb * 256 + wn * 64;
    #pragma unroll
    for (int mf = 0; mf < 8; ++mf) {
        #pragma unroll
        for (int nf = 0; nf < 4; ++nf) {
            const int col = nf * 16 + fr;
            #pragma unroll
            for (int r = 0; r < 4; ++r) {
                const int row = mf * 16 + fq * 4 + r;
                const float xv = acc[mf][nf][r] + bv[nf];
                ob[(size_t)row * DO + col] = 1.0f / (1.0f + __expf(-xv));
            }
        }
    }
#undef LOAD_X
#undef STAGE_B
#undef WRITE_A
#undef READ_A4
#undef READ_B4
#undef MFMA16
}

extern "C" void kernel_launch(void* const* d_in, const int* in_sizes, int n_in,
                              void* d_out, int out_size, void* d_ws, size_t ws_size,
                              hipStream_t stream) {
    const float* tensor    = (const float*)d_in[0];
    const int*   sel_idx   = (const int*)d_in[1];
    const float* sel_probs = (const float*)d_in[2];
    const float* W         = (const float*)d_in[3];
    const float* bias      = (const float*)d_in[4];
    float* out = (float*)d_out;

    unsigned short* wpack = (unsigned short*)d_ws;                     // 16 MiB
    float* beff = (float*)((char*)d_ws + (size_t)B_ * 4 * 16 * 32768); // +32 KiB

    hipFuncSetAttribute((const void*)gemm8,
                        hipFuncAttributeMaxDynamicSharedMemorySize, 131072);

    hipLaunchKernelGGL(prep_wpack, dim3(16, 4, 8), dim3(256), 0, stream,
                       W, sel_idx, sel_probs, wpack);
    hipLaunchKernelGGL(prep_beff, dim3(8), dim3(256), 0, stream,
                       bias, sel_idx, sel_probs, beff);
    hipLaunchKernelGGL(gemm8, dim3(512), dim3(512), 131072, stream,
                       tensor, wpack, beff, out);
}